// Round 18
// baseline (158.455 us; speedup 1.0000x reference)
//
#include <hip/hip_runtime.h>
#include <hip/hip_bf16.h>

typedef __attribute__((ext_vector_type(8))) short short8v;   // bf16x8 fragment
typedef __attribute__((ext_vector_type(4))) float float4v;   // fp32x4 accum
typedef unsigned short ushort;
typedef unsigned int uint;

namespace {

constexpr int Hh = 192, Ww = 192, Cc = 16, Oo = 64, Bb = 4;
constexpr int TH = 4, TW = 32, NT = 128;     // 4x32 pixel tile, 128 threads (2 waves)
constexpr int HW = Hh * Ww;                  // 36864
constexpr int NPL = Bb * Cc;                 // 64 planes
constexpr int PVG_PLANE = 236 * 198;         // 46728 col-prefix plane
constexpr int PHG_PLANE = 198 * 236;         // 46728 row-prefix plane
constexpr size_t PLANE = (size_t)Bb * Oo * HW;                 // 9437184 floats
constexpr size_t PREFIX_FLOATS = (size_t)NPL * (PVG_PLANE + PHG_PLANE);  // 5981184
constexpr size_t WBF_FLOATS = 65536 / 2;                       // 65536 ushorts
constexpr size_t NEED_FULL = (PREFIX_FLOATS + WBF_FLOATS + 2 * PLANE) * 4;  // 99,553,280

// Each feature = (vertical segment sum) + (horizontal segment sum), scaled by 1/n.
struct FD { int hasV; int vdj, vi0, vi1; int hasH; int hdi, hj0, hj1; float inv_n; };

constexpr FD FT[49] = {
    // 9 inner taps (i,j) row-major, n=1 (as V-singles)
    {1,-1,-1,-1, 0,0,0,0, 1.f}, {1, 0,-1,-1, 0,0,0,0, 1.f}, {1, 1,-1,-1, 0,0,0,0, 1.f},
    {1,-1, 0, 0, 0,0,0,0, 1.f}, {1, 0, 0, 0, 0,0,0,0, 1.f}, {1, 1, 0, 0, 0,0,0,0, 1.f},
    {1,-1, 1, 1, 0,0,0,0, 1.f}, {1, 0, 1, 1, 0,0,0,0, 1.f}, {1, 1, 1, 1, 0,0,0,0, 1.f},
    // ring5 (16)
    {1,-2,-2, 2, 1,-2,-1, 2, 1.f/9.f},
    {1,-1,-2, 2, 0,0,0,0, 0.2f},
    {1, 0,-2, 2, 0,0,0,0, 0.2f},
    {1, 1,-2, 2, 0,0,0,0, 0.2f},
    {1, 2,-2, 2, 1,-2,-2, 1, 1.f/9.f},
    {0,0,0,0, 1,-1,-2, 2, 0.2f},
    {0,0,0,0, 1,-1,-2, 2, 0.2f},
    {0,0,0,0, 1, 0,-2, 2, 0.2f},
    {0,0,0,0, 1, 0,-2, 2, 0.2f},
    {0,0,0,0, 1, 1,-2, 2, 0.2f},
    {0,0,0,0, 1, 1,-2, 2, 0.2f},
    {1,-2,-2, 2, 1, 2,-1, 2, 1.f/9.f},
    {1,-1,-2, 2, 0,0,0,0, 0.2f},
    {1, 0,-2, 2, 0,0,0,0, 0.2f},
    {1, 1,-2, 2, 0,0,0,0, 0.2f},
    {1, 2,-2, 2, 1, 2,-2, 1, 1.f/9.f},
    // ring7 (24)
    {1,-3,-3,11, 1,-3,-2,21, 1.f/39.f},
    {1,-2,-3,11, 0,0,0,0, 1.f/15.f},
    {1,-1,-3,11, 0,0,0,0, 1.f/15.f},
    {1, 0,-3,11, 0,0,0,0, 1.f/15.f},
    {1, 1,-3,11, 0,0,0,0, 1.f/15.f},
    {1, 2,-3,11, 0,0,0,0, 1.f/15.f},
    {1, 3,-3,11, 1,-3,-21, 2, 1.f/39.f},
    {0,0,0,0, 1,-2,-3,21, 0.04f},
    {0,0,0,0, 1,-2,-21,3, 0.04f},
    {0,0,0,0, 1,-1,-3,21, 0.04f},
    {0,0,0,0, 1,-1,-21,3, 0.04f},
    {0,0,0,0, 1, 0,-3,21, 0.04f},
    {0,0,0,0, 1, 0,-21,3, 0.04f},
    {0,0,0,0, 1, 1,-3,21, 0.04f},
    {0,0,0,0, 1, 1,-21,3, 0.04f},
    {0,0,0,0, 1, 2,-3,21, 0.04f},
    {0,0,0,0, 1, 2,-21,3, 0.04f},
    {1,-3,-11,3, 1, 3,-2,21, 1.f/39.f},
    {1,-2,-11,3, 0,0,0,0, 1.f/15.f},
    {1,-1,-11,3, 0,0,0,0, 1.f/15.f},
    {1, 0,-11,3, 0,0,0,0, 1.f/15.f},
    {1, 1,-11,3, 0,0,0,0, 1.f/15.f},
    {1, 2,-11,3, 0,0,0,0, 1.f/15.f},
    {1, 3,-11,3, 1, 3,-21,2, 1.f/39.f},
};

// reflect-pad(3) + clip index map; valid for u in [-21, 213]
__device__ __forceinline__ int mapIdx(int u) {
    if (u < 0) { u = -u; if (u > 3) u = 3; }
    else if (u > 191) { u = 382 - u; if (u < 188) u = 188; }
    return u;
}

// RNE fp32->bf16 bits (native; pairs fuse to v_cvt_pk_bf16_f32)
__device__ __forceinline__ ushort f2bf(float f) {
    __hip_bfloat16 h = __float2bfloat16(f);
    return __builtin_bit_cast(ushort, h);
}

// One-time weight prep: wbf[c][o][k] bf16, k in [0,64) padded with zeros for k>=49.
__global__ __launch_bounds__(256)
void wprep(const float* __restrict__ wgt, ushort* __restrict__ wbf) {
    const int t = blockIdx.x * 256 + threadIdx.x;   // 65536 entries
    const int k = t & 63, o = (t >> 6) & 63, c = t >> 12;
    wbf[t] = (k < 49) ? f2bf(wgt[o * 784 + c * 49 + k]) : (ushort)0;
}

// Build global prefix planes; 64-thread blocks (CU spread), 5-wide unrolled scans.
__global__ __launch_bounds__(64)
void prefixes(const float* __restrict__ x, float* __restrict__ pvg,
              float* __restrict__ phg)
{
    const int t = blockIdx.x * 64 + threadIdx.x;       // 0..25343
    if (t >= 2 * NPL * 198) return;
    const bool isPV = t < NPL * 198;
    const int u = isPV ? t : t - NPL * 198;
    const int plane = u / 198;
    const int q     = u - plane * 198;
    const float* xp = x + (size_t)plane * HW;
    if (isPV) {
        const int wsrc = mapIdx(q - 3);                // fixed source col
        float* pv = pvg + (size_t)plane * PVG_PLANE + q;
        float r = 0.f;
        pv[0] = 0.f;
        for (int t0 = 0; t0 < 235; t0 += 5) {          // 47 groups; 5 loads batched
            float v0 = xp[mapIdx(t0 - 21) * Ww + wsrc];
            float v1 = xp[mapIdx(t0 - 20) * Ww + wsrc];
            float v2 = xp[mapIdx(t0 - 19) * Ww + wsrc];
            float v3 = xp[mapIdx(t0 - 18) * Ww + wsrc];
            float v4 = xp[mapIdx(t0 - 17) * Ww + wsrc];
            float* pd = pv + (size_t)(t0 + 1) * 198;
            r += v0; pd[0]   = r;
            r += v1; pd[198] = r;
            r += v2; pd[396] = r;
            r += v3; pd[594] = r;
            r += v4; pd[792] = r;
        }
    } else {
        const int rsrc = mapIdx(q - 3) * Ww;           // fixed source row
        float* ph = phg + (size_t)plane * PHG_PLANE + (size_t)q * 236;
        float r = 0.f;
        ph[0] = 0.f;
        for (int t0 = 0; t0 < 235; t0 += 5) {
            float v0 = xp[rsrc + mapIdx(t0 - 21)];
            float v1 = xp[rsrc + mapIdx(t0 - 20)];
            float v2 = xp[rsrc + mapIdx(t0 - 19)];
            float v3 = xp[rsrc + mapIdx(t0 - 18)];
            float v4 = xp[rsrc + mapIdx(t0 - 17)];
            float* pd = ph + t0 + 1;
            r += v0; pd[0] = r;
            r += v1; pd[1] = r;
            r += v2; pd[2] = r;
            r += v3; pd[3] = r;
            r += v4; pd[4] = r;
        }
    }
}

// NC = channels per block; DIRECT: write out+bias, else fp32 partial to dst.
template<int NC, bool DIRECT>
__global__ __launch_bounds__(NT, 4)
void fova18(const ushort* __restrict__ wbf, const float* __restrict__ bias,
            const float* __restrict__ pvg, const float* __restrict__ phg,
            float* __restrict__ dst)
{
    constexpr int HALVES = Cc / NC;
    __shared__ ushort featB[NT][66];   // bf16 feat [pixel][k], padded stride (only LDS)

    const int tid  = threadIdx.x;
    const int lane = tid & 63;
    const int wv   = tid >> 6;          // wave id 0/1
    const int w0   = blockIdx.x * TW;
    const int h0   = blockIdx.y * TH;
    const int bz   = blockIdx.z;
    const int b    = (HALVES == 1) ? bz : (bz >> 1);
    const int half = (HALVES == 1) ? 0  : (bz & 1);
    const int c0   = half * NC;
    const int ph_  = tid >> 5;          // pixel row 0..3 (tid == pixel id)
    const int pw   = tid & 31;
    const int h    = h0 + ph_, w = w0 + pw;

    float4v acc[4][4];
#pragma unroll
    for (int i = 0; i < 4; ++i)
#pragma unroll
        for (int j = 0; j < 4; ++j) acc[i][j] = (float4v)(0.f);

    // one-time pad zeroing (ordered before first MFMA by the in-loop barrier)
#pragma unroll
    for (int f = 49; f < 64; ++f) featB[tid][f] = 0;

    // per-thread prefix bases (plane stride advanced per c)
    const float* pvb = pvg + (size_t)(b * Cc + c0) * PVG_PLANE + (size_t)(h + 22) * 198 + (w + 3);
    const float* phb = phg + (size_t)(b * Cc + c0) * PHG_PLANE + (size_t)(h + 3) * 236 + (w + 21);

    for (int cc = 0; cc < NC; ++cc) {
        const int c = c0 + cc;
        // ---- features straight from prefix planes (const-imm offsets) ----
        {
            const float* pv = pvb;
            const float* phv = phb;
            auto FV = [&](int f) -> float {
                float s = 0.f;
                if (FT[f].hasV) {
                    s += pv[FT[f].vi1 * 198 + FT[f].vdj] - pv[(FT[f].vi0 - 1) * 198 + FT[f].vdj];
                }
                if (FT[f].hasH) {
                    s += phv[FT[f].hdi * 236 + (FT[f].hj1 + 1)] - phv[FT[f].hdi * 236 + FT[f].hj0];
                }
                return s * FT[f].inv_n;
            };
            uint* fb32 = reinterpret_cast<uint*>(&featB[tid][0]);
#pragma unroll
            for (int j = 0; j < 24; ++j)
                fb32[j] = (uint)f2bf(FV(2 * j)) | ((uint)f2bf(FV(2 * j + 1)) << 16);
            featB[tid][48] = f2bf(FV(48));
        }
        __syncthreads();

        // ---- MFMA(c): A straight from wbf (b128 global, L2-broadcast), B from featB ----
        {
            const int olo = lane & 15, kg = lane >> 4;
#pragma unroll
            for (int kc = 0; kc < 2; ++kc) {
                const int k0 = kc * 32 + kg * 8;          // 16B aligned
                short8v afr[4];
#pragma unroll
                for (int ob = 0; ob < 4; ++ob) {
                    const int o = ob * 16 + olo;
                    afr[ob] = *(const short8v*)(&wbf[(c << 12) + (o << 6) + k0]);
                }
                short8v bfr[4];
#pragma unroll
                for (int nb = 0; nb < 4; ++nb) {
                    const int p = wv * 64 + nb * 16 + olo;
                    const uint* bp = (const uint*)(&featB[p][k0]);
                    uint4 u;
                    u.x = bp[0]; u.y = bp[1]; u.z = bp[2]; u.w = bp[3];
                    bfr[nb] = __builtin_bit_cast(short8v, u);
                }
#pragma unroll
                for (int ob = 0; ob < 4; ++ob)
#pragma unroll
                    for (int nb = 0; nb < 4; ++nb)
                        acc[ob][nb] = __builtin_amdgcn_mfma_f32_16x16x32_bf16(
                            afr[ob], bfr[nb], acc[ob][nb], 0, 0, 0);
            }
        }
        __syncthreads();   // featB rewritten next c

        pvb += PVG_PLANE; phb += PHG_PLANE;
    }

    // ---- epilogue: D frag: col(pixel)=lane&15, row(o)=(lane>>4)*4+reg ----
    float* dbase = DIRECT ? dst : (dst + (size_t)half * PLANE);
#pragma unroll
    for (int ob = 0; ob < 4; ++ob)
#pragma unroll
        for (int nb = 0; nb < 4; ++nb) {
            const int p = wv * 64 + nb * 16 + (lane & 15);
            const int hh = h0 + (p >> 5), ww2 = w0 + (p & 31);
            const int o0 = ob * 16 + ((lane >> 4) << 2);
            float4v a = acc[ob][nb];
#pragma unroll
            for (int r = 0; r < 4; ++r) {
                const int o = o0 + r;
                float v = DIRECT ? (a[r] + bias[o]) : a[r];
                dbase[(((size_t)b * Oo + o) * Hh + hh) * Ww + ww2] = v;
            }
        }
}

// out = p0 + p1 + bias (memory-bound, float4, grid-stride)
__global__ __launch_bounds__(256)
void reduce2(const float4* __restrict__ p, const float* __restrict__ bias,
             float4* __restrict__ out)
{
    const int n4 = (int)(PLANE / 4);            // 2359296
    for (int i = blockIdx.x * 256 + threadIdx.x; i < n4; i += gridDim.x * 256) {
        float4 a = p[i];
        float4 b = p[i + n4];
        const int o = (i / 9216) & 63;          // 9216 float4s per (b,o) plane
        const float bo = bias[o];
        float4 r;
        r.x = a.x + b.x + bo; r.y = a.y + b.y + bo;
        r.z = a.z + b.z + bo; r.w = a.w + b.w + bo;
        out[i] = r;
    }
}

} // namespace

extern "C" void kernel_launch(void* const* d_in, const int* in_sizes, int n_in,
                              void* d_out, int out_size, void* d_ws, size_t ws_size,
                              hipStream_t stream) {
    (void)in_sizes; (void)n_in; (void)out_size;
    const float* x    = (const float*)d_in[0];
    const float* wgt  = (const float*)d_in[1];
    const float* bias = (const float*)d_in[2];
    float* out        = (float*)d_out;

    float* pvg  = (float*)d_ws;
    float* phg  = pvg + (size_t)NPL * PVG_PLANE;
    ushort* wbf = (ushort*)(phg + (size_t)NPL * PHG_PLANE);

    prefixes<<<dim3((2 * NPL * 198 + 63) / 64), dim3(64), 0, stream>>>(x, pvg, phg);
    wprep<<<dim3(256), dim3(256), 0, stream>>>(wgt, wbf);

    dim3 block(NT);
    if (ws_size >= NEED_FULL) {
        float* part = (float*)d_ws + PREFIX_FLOATS + WBF_FLOATS;
        dim3 grid(Ww / TW, Hh / TH, Bb * 2);          // 2304 blocks, 8 channels each
        fova18<8, false><<<grid, block, 0, stream>>>(wbf, bias, pvg, phg, part);
        reduce2<<<dim3(2048), dim3(256), 0, stream>>>((const float4*)part, bias, (float4*)out);
    } else {
        dim3 grid(Ww / TW, Hh / TH, Bb);              // 1152 blocks, 16 channels
        fova18<16, true><<<grid, block, 0, stream>>>(wbf, bias, pvg, phg, out);
    }
}

// Round 19
// 145.925 us; speedup vs baseline: 1.0859x; 1.0859x over previous
//
#include <hip/hip_runtime.h>
#include <hip/hip_bf16.h>

typedef __attribute__((ext_vector_type(8))) short short8v;   // bf16x8 fragment
typedef __attribute__((ext_vector_type(4))) float float4v;   // fp32x4 accum
typedef unsigned short ushort;
typedef unsigned int uint;

namespace {

constexpr int Hh = 192, Ww = 192, Cc = 16, Oo = 64, Bb = 4;
constexpr int TH = 4, TW = 32, NT = 128;     // 4x32 pixel tile, 128 threads (2 waves)
constexpr int HW = Hh * Ww;                  // 36864
constexpr int NPL = Bb * Cc;                 // 64 planes
constexpr int PVG_PLANE = 236 * 198;         // 46728 col-prefix plane
constexpr int PHG_PLANE = 198 * 236;         // 46728 row-prefix plane
constexpr size_t PLANE = (size_t)Bb * Oo * HW;                 // 9437184 floats
constexpr size_t PREFIX_FLOATS = (size_t)NPL * (PVG_PLANE + PHG_PLANE);  // 5981184
constexpr size_t WBF_FLOATS = 65536 / 2;                       // 65536 ushorts
constexpr size_t NEED_FULL = (PREFIX_FLOATS + WBF_FLOATS + 2 * PLANE) * 4;  // 99,553,280

// Each feature = (vertical segment sum) + (horizontal segment sum), scaled by 1/n.
struct FD { int hasV; int vdj, vi0, vi1; int hasH; int hdi, hj0, hj1; float inv_n; };

constexpr FD FT[49] = {
    // 9 inner taps (i,j) row-major, n=1 (as V-singles)
    {1,-1,-1,-1, 0,0,0,0, 1.f}, {1, 0,-1,-1, 0,0,0,0, 1.f}, {1, 1,-1,-1, 0,0,0,0, 1.f},
    {1,-1, 0, 0, 0,0,0,0, 1.f}, {1, 0, 0, 0, 0,0,0,0, 1.f}, {1, 1, 0, 0, 0,0,0,0, 1.f},
    {1,-1, 1, 1, 0,0,0,0, 1.f}, {1, 0, 1, 1, 0,0,0,0, 1.f}, {1, 1, 1, 1, 0,0,0,0, 1.f},
    // ring5 (16)
    {1,-2,-2, 2, 1,-2,-1, 2, 1.f/9.f},
    {1,-1,-2, 2, 0,0,0,0, 0.2f},
    {1, 0,-2, 2, 0,0,0,0, 0.2f},
    {1, 1,-2, 2, 0,0,0,0, 0.2f},
    {1, 2,-2, 2, 1,-2,-2, 1, 1.f/9.f},
    {0,0,0,0, 1,-1,-2, 2, 0.2f},
    {0,0,0,0, 1,-1,-2, 2, 0.2f},
    {0,0,0,0, 1, 0,-2, 2, 0.2f},
    {0,0,0,0, 1, 0,-2, 2, 0.2f},
    {0,0,0,0, 1, 1,-2, 2, 0.2f},
    {0,0,0,0, 1, 1,-2, 2, 0.2f},
    {1,-2,-2, 2, 1, 2,-1, 2, 1.f/9.f},
    {1,-1,-2, 2, 0,0,0,0, 0.2f},
    {1, 0,-2, 2, 0,0,0,0, 0.2f},
    {1, 1,-2, 2, 0,0,0,0, 0.2f},
    {1, 2,-2, 2, 1, 2,-2, 1, 1.f/9.f},
    // ring7 (24)
    {1,-3,-3,11, 1,-3,-2,21, 1.f/39.f},
    {1,-2,-3,11, 0,0,0,0, 1.f/15.f},
    {1,-1,-3,11, 0,0,0,0, 1.f/15.f},
    {1, 0,-3,11, 0,0,0,0, 1.f/15.f},
    {1, 1,-3,11, 0,0,0,0, 1.f/15.f},
    {1, 2,-3,11, 0,0,0,0, 1.f/15.f},
    {1, 3,-3,11, 1,-3,-21, 2, 1.f/39.f},
    {0,0,0,0, 1,-2,-3,21, 0.04f},
    {0,0,0,0, 1,-2,-21,3, 0.04f},
    {0,0,0,0, 1,-1,-3,21, 0.04f},
    {0,0,0,0, 1,-1,-21,3, 0.04f},
    {0,0,0,0, 1, 0,-3,21, 0.04f},
    {0,0,0,0, 1, 0,-21,3, 0.04f},
    {0,0,0,0, 1, 1,-3,21, 0.04f},
    {0,0,0,0, 1, 1,-21,3, 0.04f},
    {0,0,0,0, 1, 2,-3,21, 0.04f},
    {0,0,0,0, 1, 2,-21,3, 0.04f},
    {1,-3,-11,3, 1, 3,-2,21, 1.f/39.f},
    {1,-2,-11,3, 0,0,0,0, 1.f/15.f},
    {1,-1,-11,3, 0,0,0,0, 1.f/15.f},
    {1, 0,-11,3, 0,0,0,0, 1.f/15.f},
    {1, 1,-11,3, 0,0,0,0, 1.f/15.f},
    {1, 2,-11,3, 0,0,0,0, 1.f/15.f},
    {1, 3,-11,3, 1, 3,-21,2, 1.f/39.f},
};

// reflect-pad(3) + clip index map; valid for u in [-21, 213]
__device__ __forceinline__ int mapIdx(int u) {
    if (u < 0) { u = -u; if (u > 3) u = 3; }
    else if (u > 191) { u = 382 - u; if (u < 188) u = 188; }
    return u;
}

// RNE fp32->bf16 bits (native; pairs fuse to v_cvt_pk_bf16_f32)
__device__ __forceinline__ ushort f2bf(float f) {
    __hip_bfloat16 h = __float2bfloat16(f);
    return __builtin_bit_cast(ushort, h);
}

// One-time weight prep: wbf[c][o][k] bf16, k in [0,64) padded with zeros for k>=49.
__global__ __launch_bounds__(256)
void wprep(const float* __restrict__ wgt, ushort* __restrict__ wbf) {
    const int t = blockIdx.x * 256 + threadIdx.x;   // 65536 entries
    const int k = t & 63, o = (t >> 6) & 63, c = t >> 12;
    wbf[t] = (k < 49) ? f2bf(wgt[o * 784 + c * 49 + k]) : (ushort)0;
}

// Build global prefix planes; 64-thread blocks (CU spread), 5-wide unrolled scans.
__global__ __launch_bounds__(64)
void prefixes(const float* __restrict__ x, float* __restrict__ pvg,
              float* __restrict__ phg)
{
    const int t = blockIdx.x * 64 + threadIdx.x;       // 0..25343
    if (t >= 2 * NPL * 198) return;
    const bool isPV = t < NPL * 198;
    const int u = isPV ? t : t - NPL * 198;
    const int plane = u / 198;
    const int q     = u - plane * 198;
    const float* xp = x + (size_t)plane * HW;
    if (isPV) {
        const int wsrc = mapIdx(q - 3);                // fixed source col
        float* pv = pvg + (size_t)plane * PVG_PLANE + q;
        float r = 0.f;
        pv[0] = 0.f;
        for (int t0 = 0; t0 < 235; t0 += 5) {          // 47 groups; 5 loads batched
            float v0 = xp[mapIdx(t0 - 21) * Ww + wsrc];
            float v1 = xp[mapIdx(t0 - 20) * Ww + wsrc];
            float v2 = xp[mapIdx(t0 - 19) * Ww + wsrc];
            float v3 = xp[mapIdx(t0 - 18) * Ww + wsrc];
            float v4 = xp[mapIdx(t0 - 17) * Ww + wsrc];
            float* pd = pv + (size_t)(t0 + 1) * 198;
            r += v0; pd[0]   = r;
            r += v1; pd[198] = r;
            r += v2; pd[396] = r;
            r += v3; pd[594] = r;
            r += v4; pd[792] = r;
        }
    } else {
        const int rsrc = mapIdx(q - 3) * Ww;           // fixed source row
        float* ph = phg + (size_t)plane * PHG_PLANE + (size_t)q * 236;
        float r = 0.f;
        ph[0] = 0.f;
        for (int t0 = 0; t0 < 235; t0 += 5) {
            float v0 = xp[rsrc + mapIdx(t0 - 21)];
            float v1 = xp[rsrc + mapIdx(t0 - 20)];
            float v2 = xp[rsrc + mapIdx(t0 - 19)];
            float v3 = xp[rsrc + mapIdx(t0 - 18)];
            float v4 = xp[rsrc + mapIdx(t0 - 17)];
            float* pd = ph + t0 + 1;
            r += v0; pd[0] = r;
            r += v1; pd[1] = r;
            r += v2; pd[2] = r;
            r += v3; pd[3] = r;
            r += v4; pd[4] = r;
        }
    }
}

// NC = channels per block; DIRECT: write out+bias, else fp32 partial to dst.
template<int NC, bool DIRECT>
__global__ __launch_bounds__(NT, 3)          // 3 waves/EU: VGPR headroom (R18 lesson)
void fova19(const ushort* __restrict__ wbf, const float* __restrict__ bias,
            const float* __restrict__ pvg, const float* __restrict__ phg,
            float* __restrict__ dst)
{
    constexpr int HALVES = Cc / NC;
    __shared__ ushort featB[NT][66];   // bf16 feat [pixel][k], padded stride (only LDS)

    const int tid  = threadIdx.x;
    const int lane = tid & 63;
    const int wv   = tid >> 6;          // wave id 0/1
    const int w0   = blockIdx.x * TW;
    const int h0   = blockIdx.y * TH;
    const int bz   = blockIdx.z;
    const int b    = (HALVES == 1) ? bz : (bz >> 1);
    const int half = (HALVES == 1) ? 0  : (bz & 1);
    const int c0   = half * NC;
    const int ph_  = tid >> 5;          // pixel row 0..3 (tid == pixel id)
    const int pw   = tid & 31;
    const int h    = h0 + ph_, w = w0 + pw;

    float4v acc[4][4];
#pragma unroll
    for (int i = 0; i < 4; ++i)
#pragma unroll
        for (int j = 0; j < 4; ++j) acc[i][j] = (float4v)(0.f);

    // one-time pad zeroing (ordered before first MFMA by the in-loop barrier)
#pragma unroll
    for (int f = 49; f < 64; ++f) featB[tid][f] = 0;

    // per-thread prefix bases (plane stride advanced per c)
    const float* pvb = pvg + (size_t)(b * Cc + c0) * PVG_PLANE + (size_t)(h + 22) * 198 + (w + 3);
    const float* phb = phg + (size_t)(b * Cc + c0) * PHG_PLANE + (size_t)(h + 3) * 236 + (w + 21);
    const ushort* wp = wbf + (c0 << 12) + ((lane & 15) << 6);   // + ob*1024 + kc*32 + kg*8

    for (int cc = 0; cc < NC; ++cc) {
        // ---- A-frags: ISSUE EARLY (T14) — L2 latency hides under feat compute ----
        short8v afr[2][4];
        {
            const int kg8 = (lane >> 4) << 3;
#pragma unroll
            for (int kc = 0; kc < 2; ++kc)
#pragma unroll
                for (int ob = 0; ob < 4; ++ob)
                    afr[kc][ob] = *(const short8v*)(&wp[(ob << 10) + (kc << 5) + kg8]);
        }

        // ---- features straight from prefix planes (const-imm offsets) ----
        {
            const float* pv = pvb;
            const float* phv = phb;
            auto FV = [&](int f) -> float {
                float s = 0.f;
                if (FT[f].hasV) {
                    s += pv[FT[f].vi1 * 198 + FT[f].vdj] - pv[(FT[f].vi0 - 1) * 198 + FT[f].vdj];
                }
                if (FT[f].hasH) {
                    s += phv[FT[f].hdi * 236 + (FT[f].hj1 + 1)] - phv[FT[f].hdi * 236 + FT[f].hj0];
                }
                return s * FT[f].inv_n;
            };
            uint* fb32 = reinterpret_cast<uint*>(&featB[tid][0]);
#pragma unroll
            for (int j = 0; j < 24; ++j)
                fb32[j] = (uint)f2bf(FV(2 * j)) | ((uint)f2bf(FV(2 * j + 1)) << 16);
            featB[tid][48] = f2bf(FV(48));
        }
        __syncthreads();

        // ---- MFMA(c): A already in regs, B from featB ----
        {
            const int olo = lane & 15, kg = lane >> 4;
#pragma unroll
            for (int kc = 0; kc < 2; ++kc) {
                const int k0 = kc * 32 + kg * 8;
                short8v bfr[4];
#pragma unroll
                for (int nb = 0; nb < 4; ++nb) {
                    const int p = wv * 64 + nb * 16 + olo;
                    const uint* bp = (const uint*)(&featB[p][k0]);
                    uint4 u;
                    u.x = bp[0]; u.y = bp[1]; u.z = bp[2]; u.w = bp[3];
                    bfr[nb] = __builtin_bit_cast(short8v, u);
                }
#pragma unroll
                for (int ob = 0; ob < 4; ++ob)
#pragma unroll
                    for (int nb = 0; nb < 4; ++nb)
                        acc[ob][nb] = __builtin_amdgcn_mfma_f32_16x16x32_bf16(
                            afr[kc][ob], bfr[nb], acc[ob][nb], 0, 0, 0);
            }
        }
        __syncthreads();   // featB rewritten next c

        pvb += PVG_PLANE; phb += PHG_PLANE; wp += 4096;
    }

    // ---- epilogue: D frag: col(pixel)=lane&15, row(o)=(lane>>4)*4+reg ----
    float* dbase = DIRECT ? dst : (dst + (size_t)half * PLANE);
#pragma unroll
    for (int ob = 0; ob < 4; ++ob)
#pragma unroll
        for (int nb = 0; nb < 4; ++nb) {
            const int p = wv * 64 + nb * 16 + (lane & 15);
            const int hh = h0 + (p >> 5), ww2 = w0 + (p & 31);
            const int o0 = ob * 16 + ((lane >> 4) << 2);
            float4v a = acc[ob][nb];
#pragma unroll
            for (int r = 0; r < 4; ++r) {
                const int o = o0 + r;
                float v = DIRECT ? (a[r] + bias[o]) : a[r];
                dbase[(((size_t)b * Oo + o) * Hh + hh) * Ww + ww2] = v;
            }
        }
}

// out = p0 + p1 + bias (memory-bound, float4, grid-stride)
__global__ __launch_bounds__(256)
void reduce2(const float4* __restrict__ p, const float* __restrict__ bias,
             float4* __restrict__ out)
{
    const int n4 = (int)(PLANE / 4);            // 2359296
    for (int i = blockIdx.x * 256 + threadIdx.x; i < n4; i += gridDim.x * 256) {
        float4 a = p[i];
        float4 b = p[i + n4];
        const int o = (i / 9216) & 63;          // 9216 float4s per (b,o) plane
        const float bo = bias[o];
        float4 r;
        r.x = a.x + b.x + bo; r.y = a.y + b.y + bo;
        r.z = a.z + b.z + bo; r.w = a.w + b.w + bo;
        out[i] = r;
    }
}

} // namespace

extern "C" void kernel_launch(void* const* d_in, const int* in_sizes, int n_in,
                              void* d_out, int out_size, void* d_ws, size_t ws_size,
                              hipStream_t stream) {
    (void)in_sizes; (void)n_in; (void)out_size;
    const float* x    = (const float*)d_in[0];
    const float* wgt  = (const float*)d_in[1];
    const float* bias = (const float*)d_in[2];
    float* out        = (float*)d_out;

    float* pvg  = (float*)d_ws;
    float* phg  = pvg + (size_t)NPL * PVG_PLANE;
    ushort* wbf = (ushort*)(phg + (size_t)NPL * PHG_PLANE);

    prefixes<<<dim3((2 * NPL * 198 + 63) / 64), dim3(64), 0, stream>>>(x, pvg, phg);
    wprep<<<dim3(256), dim3(256), 0, stream>>>(wgt, wbf);

    dim3 block(NT);
    if (ws_size >= NEED_FULL) {
        float* part = (float*)d_ws + PREFIX_FLOATS + WBF_FLOATS;
        dim3 grid(Ww / TW, Hh / TH, Bb * 2);          // 2304 blocks, 8 channels each
        fova19<8, false><<<grid, block, 0, stream>>>(wbf, bias, pvg, phg, part);
        reduce2<<<dim3(2048), dim3(256), 0, stream>>>((const float4*)part, bias, (float4*)out);
    } else {
        dim3 grid(Ww / TW, Hh / TH, Bb);              // 1152 blocks, 16 channels
        fova19<16, true><<<grid, block, 0, stream>>>(wbf, bias, pvg, phg, out);
    }
}

// Round 20
// 119.028 us; speedup vs baseline: 1.3312x; 1.2260x over previous
//
#include <hip/hip_runtime.h>
#include <hip/hip_bf16.h>

typedef __attribute__((ext_vector_type(8))) short short8v;   // bf16x8 fragment
typedef __attribute__((ext_vector_type(4))) float float4v;   // fp32x4 accum
typedef unsigned short ushort;
typedef unsigned int uint;

namespace {

constexpr int Hh = 192, Ww = 192, Cc = 16, Oo = 64, Bb = 4;
constexpr int TH = 4, TW = 32, NT = 128;     // 4x32 pixel tile, 128 threads (2 waves)
constexpr int HW = Hh * Ww;                  // 36864
constexpr int NPL = Bb * Cc;                 // 64 planes
constexpr int PVG_PLANE = 236 * 198;         // 46728 col-prefix plane
constexpr int PHG_PLANE = 198 * 236;         // 46728 row-prefix plane
constexpr size_t PLANE = (size_t)Bb * Oo * HW;                 // 9437184 floats
constexpr size_t PREFIX_FLOATS = (size_t)NPL * (PVG_PLANE + PHG_PLANE);  // 5981184
constexpr size_t WBF_FLOATS = 65536 / 2;                       // 65536 ushorts
constexpr size_t NEED_FULL = (PREFIX_FLOATS + WBF_FLOATS + 2 * PLANE) * 4;  // 99,553,280

// Each feature = (vertical segment sum) + (horizontal segment sum), scaled by 1/n.
struct FD { int hasV; int vdj, vi0, vi1; int hasH; int hdi, hj0, hj1; float inv_n; };

constexpr FD FT[49] = {
    // 9 inner taps (i,j) row-major, n=1 (as V-singles)
    {1,-1,-1,-1, 0,0,0,0, 1.f}, {1, 0,-1,-1, 0,0,0,0, 1.f}, {1, 1,-1,-1, 0,0,0,0, 1.f},
    {1,-1, 0, 0, 0,0,0,0, 1.f}, {1, 0, 0, 0, 0,0,0,0, 1.f}, {1, 1, 0, 0, 0,0,0,0, 1.f},
    {1,-1, 1, 1, 0,0,0,0, 1.f}, {1, 0, 1, 1, 0,0,0,0, 1.f}, {1, 1, 1, 1, 0,0,0,0, 1.f},
    // ring5 (16)
    {1,-2,-2, 2, 1,-2,-1, 2, 1.f/9.f},
    {1,-1,-2, 2, 0,0,0,0, 0.2f},
    {1, 0,-2, 2, 0,0,0,0, 0.2f},
    {1, 1,-2, 2, 0,0,0,0, 0.2f},
    {1, 2,-2, 2, 1,-2,-2, 1, 1.f/9.f},
    {0,0,0,0, 1,-1,-2, 2, 0.2f},
    {0,0,0,0, 1,-1,-2, 2, 0.2f},
    {0,0,0,0, 1, 0,-2, 2, 0.2f},
    {0,0,0,0, 1, 0,-2, 2, 0.2f},
    {0,0,0,0, 1, 1,-2, 2, 0.2f},
    {0,0,0,0, 1, 1,-2, 2, 0.2f},
    {1,-2,-2, 2, 1, 2,-1, 2, 1.f/9.f},
    {1,-1,-2, 2, 0,0,0,0, 0.2f},
    {1, 0,-2, 2, 0,0,0,0, 0.2f},
    {1, 1,-2, 2, 0,0,0,0, 0.2f},
    {1, 2,-2, 2, 1, 2,-2, 1, 1.f/9.f},
    // ring7 (24)
    {1,-3,-3,11, 1,-3,-2,21, 1.f/39.f},
    {1,-2,-3,11, 0,0,0,0, 1.f/15.f},
    {1,-1,-3,11, 0,0,0,0, 1.f/15.f},
    {1, 0,-3,11, 0,0,0,0, 1.f/15.f},
    {1, 1,-3,11, 0,0,0,0, 1.f/15.f},
    {1, 2,-3,11, 0,0,0,0, 1.f/15.f},
    {1, 3,-3,11, 1,-3,-21, 2, 1.f/39.f},
    {0,0,0,0, 1,-2,-3,21, 0.04f},
    {0,0,0,0, 1,-2,-21,3, 0.04f},
    {0,0,0,0, 1,-1,-3,21, 0.04f},
    {0,0,0,0, 1,-1,-21,3, 0.04f},
    {0,0,0,0, 1, 0,-3,21, 0.04f},
    {0,0,0,0, 1, 0,-21,3, 0.04f},
    {0,0,0,0, 1, 1,-3,21, 0.04f},
    {0,0,0,0, 1, 1,-21,3, 0.04f},
    {0,0,0,0, 1, 2,-3,21, 0.04f},
    {0,0,0,0, 1, 2,-21,3, 0.04f},
    {1,-3,-11,3, 1, 3,-2,21, 1.f/39.f},
    {1,-2,-11,3, 0,0,0,0, 1.f/15.f},
    {1,-1,-11,3, 0,0,0,0, 1.f/15.f},
    {1, 0,-11,3, 0,0,0,0, 1.f/15.f},
    {1, 1,-11,3, 0,0,0,0, 1.f/15.f},
    {1, 2,-11,3, 0,0,0,0, 1.f/15.f},
    {1, 3,-11,3, 1, 3,-21,2, 1.f/39.f},
};

// reflect-pad(3) + clip index map; valid for u in [-21, 213]
__device__ __forceinline__ int mapIdx(int u) {
    if (u < 0) { u = -u; if (u > 3) u = 3; }
    else if (u > 191) { u = 382 - u; if (u < 188) u = 188; }
    return u;
}

// RNE fp32->bf16 bits (native; pairs fuse to v_cvt_pk_bf16_f32)
__device__ __forceinline__ ushort f2bf(float f) {
    __hip_bfloat16 h = __float2bfloat16(f);
    return __builtin_bit_cast(ushort, h);
}

// One-time weight prep: wbf[c][o][k] bf16, k in [0,64) padded with zeros for k>=49.
__global__ __launch_bounds__(256)
void wprep(const float* __restrict__ wgt, ushort* __restrict__ wbf) {
    const int t = blockIdx.x * 256 + threadIdx.x;   // 65536 entries
    const int k = t & 63, o = (t >> 6) & 63, c = t >> 12;
    wbf[t] = (k < 49) ? f2bf(wgt[o * 784 + c * 49 + k]) : (ushort)0;
}

// Build global prefix planes; 64-thread blocks (CU spread), 5-wide unrolled scans.
__global__ __launch_bounds__(64)
void prefixes(const float* __restrict__ x, float* __restrict__ pvg,
              float* __restrict__ phg)
{
    const int t = blockIdx.x * 64 + threadIdx.x;       // 0..25343
    if (t >= 2 * NPL * 198) return;
    const bool isPV = t < NPL * 198;
    const int u = isPV ? t : t - NPL * 198;
    const int plane = u / 198;
    const int q     = u - plane * 198;
    const float* xp = x + (size_t)plane * HW;
    if (isPV) {
        const int wsrc = mapIdx(q - 3);                // fixed source col
        float* pv = pvg + (size_t)plane * PVG_PLANE + q;
        float r = 0.f;
        pv[0] = 0.f;
        for (int t0 = 0; t0 < 235; t0 += 5) {          // 47 groups; 5 loads batched
            float v0 = xp[mapIdx(t0 - 21) * Ww + wsrc];
            float v1 = xp[mapIdx(t0 - 20) * Ww + wsrc];
            float v2 = xp[mapIdx(t0 - 19) * Ww + wsrc];
            float v3 = xp[mapIdx(t0 - 18) * Ww + wsrc];
            float v4 = xp[mapIdx(t0 - 17) * Ww + wsrc];
            float* pd = pv + (size_t)(t0 + 1) * 198;
            r += v0; pd[0]   = r;
            r += v1; pd[198] = r;
            r += v2; pd[396] = r;
            r += v3; pd[594] = r;
            r += v4; pd[792] = r;
        }
    } else {
        const int rsrc = mapIdx(q - 3) * Ww;           // fixed source row
        float* ph = phg + (size_t)plane * PHG_PLANE + (size_t)q * 236;
        float r = 0.f;
        ph[0] = 0.f;
        for (int t0 = 0; t0 < 235; t0 += 5) {
            float v0 = xp[rsrc + mapIdx(t0 - 21)];
            float v1 = xp[rsrc + mapIdx(t0 - 20)];
            float v2 = xp[rsrc + mapIdx(t0 - 19)];
            float v3 = xp[rsrc + mapIdx(t0 - 18)];
            float v4 = xp[rsrc + mapIdx(t0 - 17)];
            float* pd = ph + t0 + 1;
            r += v0; pd[0] = r;
            r += v1; pd[1] = r;
            r += v2; pd[2] = r;
            r += v3; pd[3] = r;
            r += v4; pd[4] = r;
        }
    }
}

// NC = channels per block; DIRECT: write out+bias, else fp32 partial to dst.
template<int NC, bool DIRECT>
__global__ __launch_bounds__(NT, 3)
void fova20(const ushort* __restrict__ wbf, const float* __restrict__ bias,
            const float* __restrict__ pvg, const float* __restrict__ phg,
            float* __restrict__ dst)
{
    constexpr int HALVES = Cc / NC;
    __shared__ ushort featB[NT][66];   // bf16 feat [pixel][k], padded stride
    __shared__ ushort wlds[64][72];    // bf16 weight slice [o][k], 144B rows (bank-spread)

    const int tid  = threadIdx.x;
    const int lane = tid & 63;
    const int wv   = tid >> 6;          // wave id 0/1
    const int w0   = blockIdx.x * TW;
    const int h0   = blockIdx.y * TH;
    const int bz   = blockIdx.z;
    const int b    = (HALVES == 1) ? bz : (bz >> 1);
    const int half = (HALVES == 1) ? 0  : (bz & 1);
    const int c0   = half * NC;
    const int ph_  = tid >> 5;          // pixel row 0..3 (tid == pixel id)
    const int pw   = tid & 31;
    const int h    = h0 + ph_, w = w0 + pw;

    float4v acc[4][4];
#pragma unroll
    for (int i = 0; i < 4; ++i)
#pragma unroll
        for (int j = 0; j < 4; ++j) acc[i][j] = (float4v)(0.f);

    // one-time pad zeroing (ordered before first MFMA by the in-loop barrier)
#pragma unroll
    for (int f = 49; f < 64; ++f) featB[tid][f] = 0;

    // per-thread prefix bases (plane stride advanced per c)
    const float* pvb = pvg + (size_t)(b * Cc + c0) * PVG_PLANE + (size_t)(h + 22) * 198 + (w + 3);
    const float* phb = phg + (size_t)(b * Cc + c0) * PHG_PLANE + (size_t)(h + 3) * 236 + (w + 21);
    // W staging: thread handles 4x16B chunks; idx = tid*4+q -> o = idx>>3, grp = idx&7
    const ushort* wsrc0 = wbf + (c0 << 12) + tid * 32;   // tid*4 chunks of 8 ushorts

    for (int cc = 0; cc < NC; ++cc) {
        // ---- W(c) staging loads: ISSUE EARLY (4x b128, 64B contiguous per thread) ----
        short8v wreg[4];
#pragma unroll
        for (int q = 0; q < 4; ++q)
            wreg[q] = *(const short8v*)(&wsrc0[q * 8]);

        // ---- features straight from prefix planes (const-imm offsets) ----
        float feat[49];
        {
            const float* pv = pvb;
            const float* phv = phb;
#pragma unroll
            for (int f = 0; f < 49; ++f) {
                float s = 0.f;
                if (FT[f].hasV) {
                    s += pv[FT[f].vi1 * 198 + FT[f].vdj] - pv[(FT[f].vi0 - 1) * 198 + FT[f].vdj];
                }
                if (FT[f].hasH) {
                    s += phv[FT[f].hdi * 236 + (FT[f].hj1 + 1)] - phv[FT[f].hdi * 236 + FT[f].hj0];
                }
                feat[f] = s * FT[f].inv_n;
            }
        }

        // ---- write wlds (W regs arrived long ago) + featB; single barrier ----
        {
            const int base = tid * 4;          // chunk index
#pragma unroll
            for (int q = 0; q < 4; ++q) {
                const int idx = base + q;
                const int o = idx >> 3, grp = idx & 7;
                *(short8v*)(&wlds[o][grp * 8]) = wreg[q];
            }
            uint* fb32 = reinterpret_cast<uint*>(&featB[tid][0]);
#pragma unroll
            for (int j = 0; j < 24; ++j)
                fb32[j] = (uint)f2bf(feat[2 * j]) | ((uint)f2bf(feat[2 * j + 1]) << 16);
            featB[tid][48] = f2bf(feat[48]);
        }
        __syncthreads();

        // ---- MFMA(c): A from wlds (ds_read_b128), B from featB ----
        {
            const int olo = lane & 15, kg = lane >> 4;
#pragma unroll
            for (int kc = 0; kc < 2; ++kc) {
                const int k0 = kc * 32 + kg * 8;          // 16B aligned in wlds
                short8v afr[4];
#pragma unroll
                for (int ob = 0; ob < 4; ++ob) {
                    const int o = ob * 16 + olo;
                    afr[ob] = *(const short8v*)(&wlds[o][k0]);
                }
                short8v bfr[4];
#pragma unroll
                for (int nb = 0; nb < 4; ++nb) {
                    const int p = wv * 64 + nb * 16 + olo;
                    const uint* bp = (const uint*)(&featB[p][k0]);
                    uint4 u;
                    u.x = bp[0]; u.y = bp[1]; u.z = bp[2]; u.w = bp[3];
                    bfr[nb] = __builtin_bit_cast(short8v, u);
                }
#pragma unroll
                for (int ob = 0; ob < 4; ++ob)
#pragma unroll
                    for (int nb = 0; nb < 4; ++nb)
                        acc[ob][nb] = __builtin_amdgcn_mfma_f32_16x16x32_bf16(
                            afr[ob], bfr[nb], acc[ob][nb], 0, 0, 0);
            }
        }
        __syncthreads();   // wlds/featB rewritten next c

        pvb += PVG_PLANE; phb += PHG_PLANE; wsrc0 += 4096;
    }

    // ---- epilogue: D frag: col(pixel)=lane&15, row(o)=(lane>>4)*4+reg ----
    float* dbase = DIRECT ? dst : (dst + (size_t)half * PLANE);
#pragma unroll
    for (int ob = 0; ob < 4; ++ob)
#pragma unroll
        for (int nb = 0; nb < 4; ++nb) {
            const int p = wv * 64 + nb * 16 + (lane & 15);
            const int hh = h0 + (p >> 5), ww2 = w0 + (p & 31);
            const int o0 = ob * 16 + ((lane >> 4) << 2);
            float4v a = acc[ob][nb];
#pragma unroll
            for (int r = 0; r < 4; ++r) {
                const int o = o0 + r;
                float v = DIRECT ? (a[r] + bias[o]) : a[r];
                dbase[(((size_t)b * Oo + o) * Hh + hh) * Ww + ww2] = v;
            }
        }
}

// out = p0 + p1 + bias (memory-bound, float4, grid-stride)
__global__ __launch_bounds__(256)
void reduce2(const float4* __restrict__ p, const float* __restrict__ bias,
             float4* __restrict__ out)
{
    const int n4 = (int)(PLANE / 4);            // 2359296
    for (int i = blockIdx.x * 256 + threadIdx.x; i < n4; i += gridDim.x * 256) {
        float4 a = p[i];
        float4 b = p[i + n4];
        const int o = (i / 9216) & 63;          // 9216 float4s per (b,o) plane
        const float bo = bias[o];
        float4 r;
        r.x = a.x + b.x + bo; r.y = a.y + b.y + bo;
        r.z = a.z + b.z + bo; r.w = a.w + b.w + bo;
        out[i] = r;
    }
}

} // namespace

extern "C" void kernel_launch(void* const* d_in, const int* in_sizes, int n_in,
                              void* d_out, int out_size, void* d_ws, size_t ws_size,
                              hipStream_t stream) {
    (void)in_sizes; (void)n_in; (void)out_size;
    const float* x    = (const float*)d_in[0];
    const float* wgt  = (const float*)d_in[1];
    const float* bias = (const float*)d_in[2];
    float* out        = (float*)d_out;

    float* pvg  = (float*)d_ws;
    float* phg  = pvg + (size_t)NPL * PVG_PLANE;
    ushort* wbf = (ushort*)(phg + (size_t)NPL * PHG_PLANE);

    prefixes<<<dim3((2 * NPL * 198 + 63) / 64), dim3(64), 0, stream>>>(x, pvg, phg);
    wprep<<<dim3(256), dim3(256), 0, stream>>>(wgt, wbf);

    dim3 block(NT);
    if (ws_size >= NEED_FULL) {
        float* part = (float*)d_ws + PREFIX_FLOATS + WBF_FLOATS;
        dim3 grid(Ww / TW, Hh / TH, Bb * 2);          // 2304 blocks, 8 channels each
        fova20<8, false><<<grid, block, 0, stream>>>(wbf, bias, pvg, phg, part);
        reduce2<<<dim3(2048), dim3(256), 0, stream>>>((const float4*)part, bias, (float4*)out);
    } else {
        dim3 grid(Ww / TW, Hh / TH, Bb);              // 1152 blocks, 16 channels
        fova20<16, true><<<grid, block, 0, stream>>>(wbf, bias, pvg, phg, out);
    }
}